// Round 5
// baseline (14977.870 us; speedup 1.0000x reference)
//
#include <hip/hip_runtime.h>
#include <math.h>

// Problem constants
#define CB 16
#define CS 400
#define CT 51
#define CTM1 50
#define CV 50000
#define CE 128
#define CH 256
#define CMAXOOV 50
#define CEXT (CV + CMAXOOV)
#define CX 640             // E + H + H  (x = [emb|ctx|h])
#define AXP 648            // padded LDS row (shorts) for x (81 short8)
#define NVB 768            // vocab-lane blocks
#define NBLK 784           // 16 state + 768 vocab
#define NTILE 782          // ceil(V/64)

typedef __attribute__((ext_vector_type(4))) float f32x4;
typedef __attribute__((ext_vector_type(8))) short short8;

__device__ __forceinline__ float wave_sum(float x) {
#pragma unroll
  for (int o = 32; o > 0; o >>= 1) x += __shfl_xor(x, o);
  return x;
}
__device__ __forceinline__ float sigm(float x) {
  return 1.f / (1.f + __expf(-x));
}
__device__ __forceinline__ float ftanh(float x) {
  x = fminf(fmaxf(x, -15.f), 15.f);
  float e = __expf(2.f * x);
  return (e - 1.f) / (e + 1.f);
}
__device__ __forceinline__ unsigned short f2bf(float f) {
  union { float f; unsigned u; } x;
  x.f = f;
  unsigned r = x.u + 0x7FFFu + ((x.u >> 16) & 1u);  // RNE
  return (unsigned short)(r >> 16);
}

// ---------------------------------------------------------------------------
// One-time weight prep
// ---------------------------------------------------------------------------
__global__ __launch_bounds__(256) void pw_convert(
    const float* __restrict__ W, unsigned short* __restrict__ Wb) {
  size_t i = ((size_t)blockIdx.x * 256 + threadIdx.x) * 8;
  float4 a = *(const float4*)(W + i);
  float4 b = *(const float4*)(W + i + 4);
  short8 o;
  o[0] = (short)f2bf(a.x); o[1] = (short)f2bf(a.y);
  o[2] = (short)f2bf(a.z); o[3] = (short)f2bf(a.w);
  o[4] = (short)f2bf(b.x); o[5] = (short)f2bf(b.y);
  o[6] = (short)f2bf(b.z); o[7] = (short)f2bf(b.w);
  *(short8*)(Wb + i) = o;
}

__global__ __launch_bounds__(256) void pw_cat(
    const float* __restrict__ W_ih, const float* __restrict__ W_hh,
    unsigned short* __restrict__ Wcat) {
  int t8 = blockIdx.x * 256 + threadIdx.x;  // 81920 short8
  int j = t8 / 80, k8 = t8 % 80;
  short8 o;
#pragma unroll
  for (int i = 0; i < 8; ++i) {
    int k = k8 * 8 + i;
    float v = (k < CE + CH) ? W_ih[(size_t)j * (CE + CH) + k]
                            : W_hh[(size_t)j * CH + (k - (CE + CH))];
    o[i] = (short)f2bf(v);
  }
  *(short8*)(Wcat + (size_t)t8 * 8) = o;
}

__global__ __launch_bounds__(256) void pw_t256(const float* __restrict__ in,
                                               float* __restrict__ out) {
  int j = blockIdx.x, k = threadIdx.x;
  out[j * CH + k] = in[k * CH + j];
}

// ---------------------------------------------------------------------------
// P0: Wh_h = enc @ W_h^T (coalesced via W_hT); copy_idx.
// ---------------------------------------------------------------------------
__global__ __launch_bounds__(256) void p0_precompute(
    const float* __restrict__ enc, const float* __restrict__ W_hT,
    const int* __restrict__ src_ids, const int* __restrict__ src_oov,
    float* __restrict__ Wh_h, int* __restrict__ copy_idx) {
  const int row0 = blockIdx.x * 8, tid = threadIdx.x;
  __shared__ float erT[CH * 8];
#pragma unroll
  for (int i = 0; i < 8; ++i) {
    int idx = tid + i * 256;
    int r = idx >> 8, j = idx & 255;
    erT[j * 8 + r] = enc[(size_t)row0 * CH + idx];
  }
  if (tid < 8) {
    int row = row0 + tid;
    int ov = src_oov[row];
    copy_idx[row] = (ov >= 0) ? (CV + ov) : src_ids[row];
  }
  __syncthreads();
  float acc[8] = {0, 0, 0, 0, 0, 0, 0, 0};
#pragma unroll 4
  for (int j = 0; j < CH; ++j) {
    float w = W_hT[j * CH + tid];
    float4 e0 = *(const float4*)&erT[j * 8];
    float4 e1 = *(const float4*)&erT[j * 8 + 4];
    acc[0] += e0.x * w; acc[1] += e0.y * w; acc[2] += e0.z * w; acc[3] += e0.w * w;
    acc[4] += e1.x * w; acc[5] += e1.y * w; acc[6] += e1.z * w; acc[7] += e1.w * w;
  }
#pragma unroll
  for (int r = 0; r < 8; ++r) Wh_h[(size_t)(row0 + r) * CH + tid] = acc[r];
}

// ---------------------------------------------------------------------------
// Z: zero control words + rowsum accumulators (every call: replay-safe).
// ctrl: [0..49]=flags, [50]=bctr, [51]=gctr
// ---------------------------------------------------------------------------
__global__ __launch_bounds__(256) void z_init(unsigned* __restrict__ ctrl,
                                              float* __restrict__ rowsum_g) {
  int tid = threadIdx.x;
  if (tid < 64) ctrl[tid] = 0u;
  for (int i = tid; i < CB * CTM1 * 16; i += 256) rowsum_g[i] = 0.f;
}

// ---------------------------------------------------------------------------
// MEGA: persistent cooperative kernel (16 state blocks + 768 vocab blocks)
// ---------------------------------------------------------------------------
__device__ __forceinline__ void spin_until(unsigned* p, unsigned target) {
  int guard = 0;
  while (__hip_atomic_load(p, __ATOMIC_RELAXED, __HIP_MEMORY_SCOPE_AGENT) <
             target &&
         ++guard < (1 << 24))
    __builtin_amdgcn_s_sleep(2);
}

__device__ __forceinline__ void barN(unsigned* ctr, unsigned target) {
  __syncthreads();
  if (threadIdx.x == 0) {
    __threadfence();
    atomicAdd(ctr, 1u);
    spin_until(ctr, target);
    __threadfence();
  }
  __syncthreads();
}

__global__ __launch_bounds__(256, 4) void mega(
    const int* __restrict__ tgt, const float* __restrict__ hidden,
    const float* __restrict__ cell, const float* __restrict__ enc,
    const int* __restrict__ src_lens, const float* __restrict__ embedding,
    const float* __restrict__ w_c, const float* __restrict__ v_vec,
    const float* __restrict__ b_attn, const float* __restrict__ b_ih,
    const float* __restrict__ b_hh, const float* __restrict__ W_pg,
    const float* __restrict__ b_pg, const float* __restrict__ b_out,
    const float* __restrict__ Wh_h, const float* __restrict__ W_sT,
    const unsigned short* __restrict__ Wcat,
    const unsigned short* __restrict__ Wb, const int* __restrict__ copy_idx,
    unsigned short* __restrict__ x_g16, unsigned short* __restrict__ A_slabs,
    float* __restrict__ attn_g, float* __restrict__ p_gen_g,
    float* __restrict__ rowsum_g, float* __restrict__ h_new_g,
    float* __restrict__ c_g, float* __restrict__ covloss_b,
    unsigned* __restrict__ ctrl, float* __restrict__ dout) {
  const int bid = blockIdx.x, tid = threadIdx.x;
  const int lane = tid & 63, wv = tid >> 6;
  unsigned* flags = ctrl;       // [50]
  unsigned* bctr = ctrl + 50;   // state-lane barrier counter
  unsigned* gctr = ctrl + 51;   // grid barrier counter

  __shared__ float cov_s[CS];
  __shared__ float a_s[CS];
  __shared__ float h_cur[CH];
  __shared__ float hws_s[CH];
  __shared__ float ctx_s[CH];
  __shared__ float red[4];
  __shared__ float stat[4];
  __shared__ float prs[4][16];
  __shared__ float gsh[4][CB][16];
  __shared__ __align__(16) short x_sh[CB * AXP];

  if (bid < CB) {
    // ======================= STATE LANE (batch b) =======================
    const int b = bid;
    const int len = src_lens[b];
    const float ba = b_attn[0];
    const int k4 = lane * 4;
    const float4 wc4 = *(const float4*)(w_c + k4);
    const float4 vv4 = *(const float4*)(v_vec + k4);
    float covl = 0.f;
    float emb_v = 0.f;
    unsigned nbar = 0;

    for (int i = tid; i < CS; i += 256) cov_s[i] = 0.f;
    h_cur[tid] = hidden[b * CH + tid];
    c_g[b * CH + tid] = cell[b * CH + tid];
    __syncthreads();
    {
      float acc = 0.f;
#pragma unroll 8
      for (int j = 0; j < CH; ++j) acc += h_cur[j] * W_sT[j * CH + tid];
      hws_s[tid] = acc;
    }
    __syncthreads();

    for (int t = 0; t < CTM1; ++t) {
      // --- phase 1: coverage update + scores + softmax + ctx + x assembly
      if (t > 0) {
        for (int s = tid; s < CS; s += 256) {
          float a = a_s[s], cv = cov_s[s];
          covl += fminf(a, cv);
          cov_s[s] = cv + a;
        }
        __syncthreads();
      }
      float ps = 0.f;
      for (int s = wv; s < CS; s += 4) {
        float cv = cov_s[s];
        float4 wh = *(const float4*)(Wh_h + ((size_t)(b * CS + s)) * CH + k4);
        float x0 = wh.x + hws_s[k4] + cv * wc4.x + ba;
        float x1 = wh.y + hws_s[k4 + 1] + cv * wc4.y + ba;
        float x2 = wh.z + hws_s[k4 + 2] + cv * wc4.z + ba;
        float x3 = wh.w + hws_s[k4 + 3] + cv * wc4.w + ba;
        float p = ftanh(x0) * vv4.x + ftanh(x1) * vv4.y + ftanh(x2) * vv4.z +
                  ftanh(x3) * vv4.w;
        p = wave_sum(p);
        if (lane == 0) {
          float e = (s < len) ? __expf(p) : 0.f;  // |score| small: no max
          a_s[s] = e;
          ps += e;
        }
      }
      if (lane == 0) red[wv] = ps;
      __syncthreads();
      if (tid == 0) stat[0] = 1.f / (red[0] + red[1] + red[2] + red[3]);
      __syncthreads();
      const float inv = stat[0];
      for (int s = tid; s < CS; s += 256) {
        float a = a_s[s] * inv;
        a_s[s] = a;
        attn_g[((size_t)t * CB + b) * CS + s] = a;
      }
      __syncthreads();
      float pc = 0.f;
      {
        const float* er = enc + ((size_t)b * CS) * CH + tid;
#pragma unroll 16
        for (int s = 0; s < CS; ++s) pc += a_s[s] * er[(size_t)s * CH];
      }
      ctx_s[tid] = pc;
      int tok = tgt[b * CT + t];
      if (tid < CE) emb_v = embedding[(size_t)tok * CE + tid];
      x_g16[b * CX + CE + tid] = f2bf(pc);
      x_g16[b * CX + CE + CH + tid] = f2bf(h_cur[tid]);
      if (tid < CE) x_g16[b * CX + tid] = f2bf(emb_v);
      A_slabs[((size_t)t * CB + b) * (2 * CH) + CH + tid] = f2bf(pc);
      barN(bctr, 16u * (++nbar));
      // --- phase 2: gates MFMA; this block owns cols {w*256 + b*16 + [0,16)}
      {
        const short8* xg8 = (const short8*)x_g16;
        short8* x8 = (short8*)x_sh;
        for (int i = tid; i < CB * (CX / 8); i += 256) {
          int bb = i / 80, c8 = i % 80;
          x8[bb * 81 + c8] = xg8[i];
        }
      }
      __syncthreads();
      {
        const int nn = lane & 15, g = lane >> 4;
        const int n0 = wv * 256 + b * 16;
        const short8* ap8 = (const short8*)(x_sh + nn * AXP);
        const short8* bp8 = (const short8*)Wcat + (size_t)(n0 + nn) * 80;
        f32x4 acc = {0.f, 0.f, 0.f, 0.f};
#pragma unroll
        for (int kt = 0; kt < 20; ++kt)
          acc = __builtin_amdgcn_mfma_f32_16x16x32_bf16(
              ap8[kt * 4 + g], bp8[kt * 4 + g], acc, 0, 0, 0);
        float bias = b_ih[n0 + nn] + b_hh[n0 + nn];
#pragma unroll
        for (int r = 0; r < 4; ++r) gsh[wv][g * 4 + r][nn] = acc[r] + bias;
      }
      __syncthreads();
      {
        int bb = tid >> 4, kk = tid & 15, kg = b * 16 + kk;
        float gi = gsh[0][bb][kk], gf = gsh[1][bb][kk];
        float gg = gsh[2][bb][kk], go = gsh[3][bb][kk];
        float co = c_g[bb * CH + kg];
        float cn = sigm(gf) * co + sigm(gi) * ftanh(gg);
        float hn = sigm(go) * ftanh(cn);
        c_g[bb * CH + kg] = cn;
        h_new_g[bb * CH + kg] = hn;
        A_slabs[((size_t)t * CB + bb) * (2 * CH) + kg] = f2bf(hn);
      }
      barN(bctr, 16u * (++nbar));
      // --- phase 3: reload h, hWs(next), p_gen, release vocab flag
      h_cur[tid] = h_new_g[b * CH + tid];
      __syncthreads();
      {
        float acc = 0.f;
#pragma unroll 8
        for (int j = 0; j < CH; ++j) acc += h_cur[j] * W_sT[j * CH + tid];
        hws_s[tid] = acc;
      }
      float z = h_cur[tid] * W_pg[tid] + ctx_s[tid] * W_pg[CH + tid];
      if (tid < CE) z += emb_v * W_pg[2 * CH + tid];
      z = wave_sum(z);
      if (lane == 0) red[wv] = z;
      __syncthreads();
      if (tid == 0) {
        p_gen_g[t * CB + b] =
            sigm(red[0] + red[1] + red[2] + red[3] + b_pg[0]);
        __threadfence();
        atomicAdd(&flags[t], 1u);
      }
      __syncthreads();
    }
    // covloss for t=49 (attn_49 vs cov_49), then block-reduce total
    for (int s = tid; s < CS; s += 256) covl += fminf(a_s[s], cov_s[s]);
    covl = wave_sum(covl);
    if (lane == 0) red[wv] = covl;
    __syncthreads();
    if (tid == 0) covloss_b[b] = red[0] + red[1] + red[2] + red[3];
  } else {
    // ======================= VOCAB LANE =======================
    const int vb = bid - CB;
    const int nn = lane & 15, g = lane >> 4;
    for (int t = 0; t < CTM1; ++t) {
      if (tid == 0) spin_until(&flags[t], 16u);
      __syncthreads();
      __threadfence();
      const short8* ap = (const short8*)(A_slabs + (size_t)t * CB * (2 * CH));
      short8 af[16];
#pragma unroll
      for (int kt = 0; kt < 16; ++kt) af[kt] = ap[nn * 64 + kt * 4 + g];
      for (int tile = vb; tile < NTILE; tile += NVB) {
        int v = tile * 64 + wv * 16 + nn;
        bool ok = v < CV;
        int vc = ok ? v : CV - 1;
        const short8* bp = (const short8*)Wb + (size_t)vc * 64;
        f32x4 acc = {0.f, 0.f, 0.f, 0.f};
#pragma unroll
        for (int kt = 0; kt < 16; ++kt)
          acc = __builtin_amdgcn_mfma_f32_16x16x32_bf16(af[kt], bp[kt * 4 + g],
                                                        acc, 0, 0, 0);
        float bo = ok ? b_out[v] : 0.f;
        float ev[4];
#pragma unroll
        for (int r = 0; r < 4; ++r) {
          float e = ok ? __expf(acc[r] + bo) : 0.f;
          if (ok)
            dout[((size_t)((g * 4 + r) * CTM1 + t)) * CEXT + v] = e;
#pragma unroll
          for (int o = 1; o < 16; o <<= 1) e += __shfl_xor(e, o);
          ev[r] = e;
        }
        if (nn == 0) {
#pragma unroll
          for (int r = 0; r < 4; ++r) prs[wv][g * 4 + r] = ev[r];
        }
        __syncthreads();
        if (tid < 16)
          atomicAdd(&rowsum_g[((size_t)t * CB + tid) * 16],
                    prs[0][tid] + prs[1][tid] + prs[2][tid] + prs[3][tid]);
        __syncthreads();
      }
    }
  }

  // ======================= POST-PASS =======================
  barN(gctr, (unsigned)NBLK);  // grid barrier #1
  for (int R = bid; R < CB * CTM1; R += NBLK) {
    int b = R / CTM1, t = R % CTM1;
    if (tid == 0)
      stat[0] = p_gen_g[t * CB + b] / rowsum_g[((size_t)t * CB + b) * 16];
    __syncthreads();
    float inv = stat[0];
    float* drow = dout + (size_t)R * CEXT;
    for (int v = tid; v < CEXT; v += 256)
      drow[v] = (v < CV) ? drow[v] * inv : 0.f;
    __syncthreads();
  }
  if (bid == 0) {  // tails: hT, cT, coverage loss
    const size_t D0 = (size_t)CB * CTM1 * CEXT;
    for (int i = tid; i < CB * CH; i += 256) {
      dout[D0 + i] = h_new_g[i];
      dout[D0 + CB * CH + i] = c_g[i];
    }
    if (tid == 0) {
      float s = 0.f;
      for (int i = 0; i < CB; ++i) s += covloss_b[i];
      dout[D0 + 2 * CB * CH] = s / (float)(CTM1 * CB);
    }
  }
  barN(gctr, 2u * (unsigned)NBLK);  // grid barrier #2
  for (int R = bid; R < CB * CTM1; R += NBLK) {
    int b = R / CTM1, t = R % CTM1;
    float pg1 = 1.f - p_gen_g[t * CB + b];
    const float* ar = attn_g + ((size_t)t * CB + b) * CS;
    float* drow = dout + (size_t)R * CEXT;
    for (int s = tid; s < CS; s += 256)
      atomicAdd(drow + copy_idx[b * CS + s], pg1 * ar[s]);
  }
}

// ---------------------------------------------------------------------------
extern "C" void kernel_launch(void* const* d_in, const int* in_sizes, int n_in,
                              void* d_out, int out_size, void* d_ws,
                              size_t ws_size, hipStream_t stream) {
  const int* tgt = (const int*)d_in[0];
  const float* hidden = (const float*)d_in[1];
  const float* cell = (const float*)d_in[2];
  const float* enc = (const float*)d_in[3];
  const int* src_lens = (const int*)d_in[4];
  const int* src_ids = (const int*)d_in[5];
  const int* src_oov = (const int*)d_in[6];
  const float* embedding = (const float*)d_in[7];
  const float* W_h = (const float*)d_in[8];
  const float* W_s = (const float*)d_in[9];
  const float* w_c = (const float*)d_in[10];
  const float* v_vec = (const float*)d_in[11];
  const float* b_attn = (const float*)d_in[12];
  const float* W_ih = (const float*)d_in[13];
  const float* W_hh = (const float*)d_in[14];
  const float* b_ih = (const float*)d_in[15];
  const float* b_hh = (const float*)d_in[16];
  const float* W_pg = (const float*)d_in[17];
  const float* b_pg = (const float*)d_in[18];
  const float* W_out = (const float*)d_in[19];
  const float* b_out = (const float*)d_in[20];
  float* dout = (float*)d_out;

  // workspace layout (all 16B-aligned)
  float* ws = (float*)d_ws;
  float* Wh_h = ws;                                  // 1,638,400
  float* W_sT = Wh_h + (size_t)CB * CS * CH;         // 65,536
  float* W_hT = W_sT + CH * CH;                      // 65,536
  float* attn_g = W_hT + CH * CH;                    // 320,000
  float* p_gen_g = attn_g + (size_t)CTM1 * CB * CS;  // 800
  float* rowsum_g = p_gen_g + CTM1 * CB;             // 12,800 (16-pad)
  float* h_new_g = rowsum_g + CTM1 * CB * 16;        // 4,096
  float* c_g = h_new_g + CB * CH;                    // 4,096
  float* covloss_b = c_g + CB * CH;                  // 16
  int* copy_idx = (int*)(covloss_b + 16);            // 6,400 ints
  unsigned* ctrl = (unsigned*)(copy_idx + CB * CS);  // 64 u32
  unsigned short* x_g16 = (unsigned short*)(ctrl + 64);         // 10,240
  unsigned short* A_slabs = x_g16 + CB * CX;         // 409,600
  unsigned short* Wcat = A_slabs + (size_t)CTM1 * CB * 2 * CH;  // 655,360
  unsigned short* Wb = Wcat + (size_t)(4 * CH) * CX; // 25,600,000

  z_init<<<1, 256, 0, stream>>>(ctrl, rowsum_g);
  pw_convert<<<(CV * 2 * CH) / (256 * 8), 256, 0, stream>>>(W_out, Wb);
  pw_cat<<<((4 * CH) * CX / 8) / 256, 256, 0, stream>>>(W_ih, W_hh, Wcat);
  pw_t256<<<CH, CH, 0, stream>>>(W_s, W_sT);
  pw_t256<<<CH, CH, 0, stream>>>(W_h, W_hT);
  p0_precompute<<<CB * CS / 8, 256, 0, stream>>>(enc, W_hT, src_ids, src_oov,
                                                 Wh_h, copy_idx);

  void* kargs[] = {
      (void*)&tgt,     (void*)&hidden,   (void*)&cell,    (void*)&enc,
      (void*)&src_lens,(void*)&embedding,(void*)&w_c,     (void*)&v_vec,
      (void*)&b_attn,  (void*)&b_ih,     (void*)&b_hh,    (void*)&W_pg,
      (void*)&b_pg,    (void*)&b_out,    (void*)&Wh_h,    (void*)&W_sT,
      (void*)&Wcat,    (void*)&Wb,       (void*)&copy_idx,(void*)&x_g16,
      (void*)&A_slabs, (void*)&attn_g,   (void*)&p_gen_g, (void*)&rowsum_g,
      (void*)&h_new_g, (void*)&c_g,      (void*)&covloss_b,(void*)&ctrl,
      (void*)&dout};
  hipError_t e = hipLaunchCooperativeKernel((const void*)mega, dim3(NBLK),
                                            dim3(256), kargs, 0, stream);
  if (e != hipSuccess) {
    // co-residency holds at this occupancy; plain launch as fallback
    hipLaunchKernelGGL(mega, dim3(NBLK), dim3(256), 0, stream, tgt, hidden,
                       cell, enc, src_lens, embedding, w_c, v_vec, b_attn,
                       b_ih, b_hh, W_pg, b_pg, b_out, Wh_h, W_sT, Wcat, Wb,
                       copy_idx, x_g16, A_slabs, attn_g, p_gen_g, rowsum_g,
                       h_new_g, c_g, covloss_b, ctrl, dout);
  }
}

// Round 6
// 9835.921 us; speedup vs baseline: 1.5228x; 1.5228x over previous
//
#include <hip/hip_runtime.h>
#include <math.h>

// Problem constants
#define CB 16
#define CS 400
#define CT 51
#define CTM1 50
#define CV 50000
#define CE 128
#define CH 256
#define CMAXOOV 50
#define CEXT (CV + CMAXOOV)
#define CX 640             // E + H + H  (x = [emb|ctx|h])
#define AXP 648            // padded LDS row (shorts) for x (81 short8)
#define NVB 768            // vocab-lane blocks
#define NBLK 784           // 16 state + 768 vocab
#define NTILE 782          // ceil(V/64)

typedef __attribute__((ext_vector_type(4))) float f32x4;
typedef __attribute__((ext_vector_type(8))) short short8;
typedef unsigned int U32;
typedef unsigned long long U64;

__device__ __forceinline__ float wave_sum(float x) {
#pragma unroll
  for (int o = 32; o > 0; o >>= 1) x += __shfl_xor(x, o);
  return x;
}
__device__ __forceinline__ float sigm(float x) {
  return 1.f / (1.f + __expf(-x));
}
__device__ __forceinline__ float ftanh(float x) {
  x = fminf(fmaxf(x, -15.f), 15.f);
  float e = __expf(2.f * x);
  return (e - 1.f) / (e + 1.f);
}
__device__ __forceinline__ unsigned short f2bf(float f) {
  union { float f; U32 u; } x;
  x.f = f;
  U32 r = x.u + 0x7FFFu + ((x.u >> 16) & 1u);  // RNE
  return (unsigned short)(r >> 16);
}
__device__ __forceinline__ float bf2f(unsigned short u) {
  U32 x = ((U32)u) << 16;
  return __uint_as_float(x);
}
__device__ __forceinline__ U64 pack4(float a, float b, float c, float d) {
  return (U64)f2bf(a) | ((U64)f2bf(b) << 16) | ((U64)f2bf(c) << 32) |
         ((U64)f2bf(d) << 48);
}
// cache-bypassing (device-coherent) loads/stores — NO fences anywhere in loop
__device__ __forceinline__ U32 ald32(const U32* p) {
  return __hip_atomic_load(p, __ATOMIC_RELAXED, __HIP_MEMORY_SCOPE_AGENT);
}
__device__ __forceinline__ U64 ald64(const U64* p) {
  return __hip_atomic_load(p, __ATOMIC_RELAXED, __HIP_MEMORY_SCOPE_AGENT);
}
__device__ __forceinline__ void ast32(U32* p, U32 v) {
  __hip_atomic_store(p, v, __ATOMIC_RELAXED, __HIP_MEMORY_SCOPE_AGENT);
}
__device__ __forceinline__ void ast64(U64* p, U64 v) {
  __hip_atomic_store(p, v, __ATOMIC_RELAXED, __HIP_MEMORY_SCOPE_AGENT);
}
#define VM0 asm volatile("s_waitcnt vmcnt(0)" ::: "memory")

// ---------------------------------------------------------------------------
// One-time weight prep
// ---------------------------------------------------------------------------
__global__ __launch_bounds__(256) void pw_convert(
    const float* __restrict__ W, unsigned short* __restrict__ Wb) {
  size_t i = ((size_t)blockIdx.x * 256 + threadIdx.x) * 8;
  float4 a = *(const float4*)(W + i);
  float4 b = *(const float4*)(W + i + 4);
  short8 o;
  o[0] = (short)f2bf(a.x); o[1] = (short)f2bf(a.y);
  o[2] = (short)f2bf(a.z); o[3] = (short)f2bf(a.w);
  o[4] = (short)f2bf(b.x); o[5] = (short)f2bf(b.y);
  o[6] = (short)f2bf(b.z); o[7] = (short)f2bf(b.w);
  *(short8*)(Wb + i) = o;
}

__global__ __launch_bounds__(256) void pw_cat(
    const float* __restrict__ W_ih, const float* __restrict__ W_hh,
    unsigned short* __restrict__ Wcat) {
  int t8 = blockIdx.x * 256 + threadIdx.x;  // 81920 short8
  int j = t8 / 80, k8 = t8 % 80;
  short8 o;
#pragma unroll
  for (int i = 0; i < 8; ++i) {
    int k = k8 * 8 + i;
    float v = (k < CE + CH) ? W_ih[(size_t)j * (CE + CH) + k]
                            : W_hh[(size_t)j * CH + (k - (CE + CH))];
    o[i] = (short)f2bf(v);
  }
  *(short8*)(Wcat + (size_t)t8 * 8) = o;
}

__global__ __launch_bounds__(256) void pw_t256(const float* __restrict__ in,
                                               float* __restrict__ out) {
  int j = blockIdx.x, k = threadIdx.x;
  out[j * CH + k] = in[k * CH + j];
}

// ---------------------------------------------------------------------------
// P0: Wh_h = enc @ W_h^T (coalesced via W_hT); copy_idx.
// ---------------------------------------------------------------------------
__global__ __launch_bounds__(256) void p0_precompute(
    const float* __restrict__ enc, const float* __restrict__ W_hT,
    const int* __restrict__ src_ids, const int* __restrict__ src_oov,
    float* __restrict__ Wh_h, int* __restrict__ copy_idx) {
  const int row0 = blockIdx.x * 8, tid = threadIdx.x;
  __shared__ float erT[CH * 8];
#pragma unroll
  for (int i = 0; i < 8; ++i) {
    int idx = tid + i * 256;
    int r = idx >> 8, j = idx & 255;
    erT[j * 8 + r] = enc[(size_t)row0 * CH + idx];
  }
  if (tid < 8) {
    int row = row0 + tid;
    int ov = src_oov[row];
    copy_idx[row] = (ov >= 0) ? (CV + ov) : src_ids[row];
  }
  __syncthreads();
  float acc[8] = {0, 0, 0, 0, 0, 0, 0, 0};
#pragma unroll 4
  for (int j = 0; j < CH; ++j) {
    float w = W_hT[j * CH + tid];
    float4 e0 = *(const float4*)&erT[j * 8];
    float4 e1 = *(const float4*)&erT[j * 8 + 4];
    acc[0] += e0.x * w; acc[1] += e0.y * w; acc[2] += e0.z * w; acc[3] += e0.w * w;
    acc[4] += e1.x * w; acc[5] += e1.y * w; acc[6] += e1.z * w; acc[7] += e1.w * w;
  }
#pragma unroll
  for (int r = 0; r < 8; ++r) Wh_h[(size_t)(row0 + r) * CH + tid] = acc[r];
}

// ---------------------------------------------------------------------------
// Z: zero control words + rowsum partials (every call: replay-safe).
// ctrl layout: arrive1[16*16], arrive2[16*16], release[64*16]  (u32)
// ---------------------------------------------------------------------------
__global__ __launch_bounds__(256) void z_init(U32* __restrict__ ctrl,
                                              float* __restrict__ part) {
  int tid = blockIdx.x * 256 + threadIdx.x;
  if (tid < 1536) ctrl[tid] = 0u;
  for (int i = tid; i < CTM1 * CB * 64; i += 256 * 64) part[i] = 0.f;
}

// ---------------------------------------------------------------------------
// MEGA: persistent kernel, 16 state blocks + 768 vocab blocks.
// No fences in the loop; cross-block data via write-through atomics;
// distributed arrive-word barriers; replicated release flags.
// ---------------------------------------------------------------------------
__device__ __forceinline__ void bar16(U32* arr, U32 target, int lane, int wv) {
  if (wv == 0) {
    int gg = 0;
    while (gg < (1 << 20)) {
      U32 v = (lane < 16) ? ald32(&arr[lane * 16]) : target;
      if (__all(v >= target)) break;
      __builtin_amdgcn_s_sleep(1);
      ++gg;
    }
  }
  __syncthreads();
}

__global__ __launch_bounds__(256, 4) void mega(
    const int* __restrict__ tgt, const float* __restrict__ hidden,
    const float* __restrict__ cell, const float* __restrict__ enc,
    const int* __restrict__ src_lens, const float* __restrict__ embedding,
    const float* __restrict__ w_c, const float* __restrict__ v_vec,
    const float* __restrict__ b_attn, const float* __restrict__ b_ih,
    const float* __restrict__ b_hh, const float* __restrict__ W_pg,
    const float* __restrict__ b_pg, const float* __restrict__ b_out,
    const float* __restrict__ Wh_h, const float* __restrict__ W_sT,
    const unsigned short* __restrict__ Wcat,
    const unsigned short* __restrict__ Wb, U64* __restrict__ Xg,
    U64* __restrict__ A64, U64* __restrict__ Hex,
    unsigned short* __restrict__ attn16, float* __restrict__ p_gen_g,
    float* __restrict__ part, float* __restrict__ c_fin,
    float* __restrict__ covloss_b, U32* __restrict__ ctrl,
    float* __restrict__ dout) {
  const int bid = blockIdx.x, tid = threadIdx.x;
  const int lane = tid & 63, wv = tid >> 6;
  U32* arrive1 = ctrl;          // 16 slots, stride 16
  U32* arrive2 = ctrl + 256;    // 16 slots, stride 16
  U32* release = ctrl + 512;    // 64 replicas, stride 16

  __shared__ __align__(16) U64 sh_big[2592];  // state: x LDS / vocab: A LDS
  __shared__ float cov_s[CS];
  __shared__ float a_s[CS];
  __shared__ __align__(16) float h_cur[CH];
  __shared__ float hws_s[CH];
  __shared__ __align__(16) float ctx_s[CH];
  __shared__ float red[4];
  __shared__ float stat[4];
  __shared__ float prs[4][16];
  __shared__ float gsh[4][CB][16];
  __shared__ float rsum_loc[16];

  if (bid < CB) {
    // ======================= STATE LANE (batch b) =======================
    const int b = bid;
    const int len = src_lens[b];
    const float ba = b_attn[0];
    const int k4 = lane * 4;
    const float4 wc4 = *(const float4*)(w_c + k4);
    const float4 vv4 = *(const float4*)(v_vec + k4);
    float covl = 0.f;
    float emb_v = 0.f;
    U64* ldsx = sh_big;  // [16][162] u64 == [16][AXP] shorts
    short* x_sh = (short*)sh_big;

    for (int i = tid; i < CS; i += 256) cov_s[i] = 0.f;
    h_cur[tid] = hidden[b * CH + tid];
    float c_reg = cell[(tid >> 4) * CH + b * 16 + (tid & 15)];
    __syncthreads();
    {
      float acc = 0.f;
#pragma unroll 8
      for (int j = 0; j < CH; ++j) acc += h_cur[j] * W_sT[j * CH + tid];
      hws_s[tid] = acc;
    }
    __syncthreads();

    for (int t = 0; t < CTM1; ++t) {
      // ---- phase A: coverage + scores(no-max exp) + softmax + ctx + packs
      if (t > 0) {
        for (int s = tid; s < CS; s += 256) {
          float a = a_s[s], cv = cov_s[s];
          covl += fminf(a, cv);
          cov_s[s] = cv + a;
        }
        __syncthreads();
      }
      float ps = 0.f;
      for (int s = wv; s < CS; s += 4) {
        float cv = cov_s[s];
        float4 wh = *(const float4*)(Wh_h + ((size_t)(b * CS + s)) * CH + k4);
        float p = ftanh(wh.x + hws_s[k4] + cv * wc4.x + ba) * vv4.x +
                  ftanh(wh.y + hws_s[k4 + 1] + cv * wc4.y + ba) * vv4.y +
                  ftanh(wh.z + hws_s[k4 + 2] + cv * wc4.z + ba) * vv4.z +
                  ftanh(wh.w + hws_s[k4 + 3] + cv * wc4.w + ba) * vv4.w;
        p = wave_sum(p);
        if (lane == 0) {
          float e = (s < len) ? __expf(p) : 0.f;  // |score| small: no max
          a_s[s] = e;
          ps += e;
        }
      }
      if (lane == 0) red[wv] = ps;
      __syncthreads();
      if (tid == 0) stat[0] = 1.f / (red[0] + red[1] + red[2] + red[3]);
      __syncthreads();
      const float inv = stat[0];
      for (int s = tid; s < CS; s += 256) {
        float a = a_s[s] * inv;
        a_s[s] = a;
        attn16[((size_t)t * CB + b) * CS + s] = f2bf(a);
      }
      __syncthreads();
      {
        float pc = 0.f;
        const float* er = enc + ((size_t)b * CS) * CH + tid;
#pragma unroll 16
        for (int s = 0; s < CS; ++s) pc += a_s[s] * er[(size_t)s * CH];
        ctx_s[tid] = pc;
      }
      const int tok = tgt[b * CT + t];
      if (tid < CE) emb_v = embedding[(size_t)tok * CE + tid];
      __syncthreads();  // ctx_s ready for packers
      if (tid < 160) {  // x = [emb|ctx|h] bf16, 4 shorts per u64
        U64 w;
        if (tid < 32) {
          float4 e = *(const float4*)(embedding + (size_t)tok * CE + 4 * tid);
          w = pack4(e.x, e.y, e.z, e.w);
        } else if (tid < 96) {
          float4 cv4 = *(const float4*)(ctx_s + 4 * (tid - 32));
          w = pack4(cv4.x, cv4.y, cv4.z, cv4.w);
        } else {
          float4 hv4 = *(const float4*)(h_cur + 4 * (tid - 96));
          w = pack4(hv4.x, hv4.y, hv4.z, hv4.w);
        }
        ast64(&Xg[b * 160 + tid], w);
      }
      if (tid < 64) {  // A slab ctx half (u64 idx 64..127 of row b)
        float4 c0 = *(const float4*)(ctx_s + 4 * tid);
        ast64(&A64[(size_t)t * 2048 + b * 128 + 64 + tid],
              pack4(c0.x, c0.y, c0.z, c0.w));
      }
      VM0;
      if (tid == 0) ast32(&arrive1[b * 16], (U32)(t + 1));
      bar16(arrive1, (U32)(t + 1), lane, wv);
      // ---- phase B: stage x (uncached) -> LDS; gates MFMA; cell update
#pragma unroll
      for (int i = 0; i < 10; ++i) {
        int idx = tid + i * 256;  // 2560 u64
        int bb = idx / 160;
        ldsx[bb * 162 + (idx - bb * 160)] = ald64(&Xg[idx]);
      }
      __syncthreads();
      {
        const int nn = lane & 15, g = lane >> 4;
        const int n0 = wv * 256 + b * 16;
        const short8* ap8 = (const short8*)(x_sh + nn * AXP);
        const short8* bp8 = (const short8*)Wcat + (size_t)(n0 + nn) * 80;
        f32x4 acc = {0.f, 0.f, 0.f, 0.f};
#pragma unroll
        for (int kt = 0; kt < 20; ++kt)
          acc = __builtin_amdgcn_mfma_f32_16x16x32_bf16(
              ap8[kt * 4 + g], bp8[kt * 4 + g], acc, 0, 0, 0);
        float bias = b_ih[n0 + nn] + b_hh[n0 + nn];
#pragma unroll
        for (int r = 0; r < 4; ++r) gsh[wv][g * 4 + r][nn] = acc[r] + bias;
      }
      __syncthreads();
      {
        int bb = tid >> 4, kk = tid & 15;
        float gi = gsh[0][bb][kk], gf = gsh[1][bb][kk];
        float gg2 = gsh[2][bb][kk], go = gsh[3][bb][kk];
        float cn = sigm(gf) * c_reg + sigm(gi) * ftanh(gg2);
        c_reg = cn;
        float hn = sigm(go) * ftanh(cn);
        float h1 = __shfl_down(hn, 1);
        float h2 = __shfl_down(hn, 2);
        float h3 = __shfl_down(hn, 3);
        if (!(kk & 1)) {  // fp32 h exchange, 2 floats per u64
          U64 w = (U64)__float_as_uint(hn) | ((U64)__float_as_uint(h1) << 32);
          ast64(&Hex[bb * 128 + b * 8 + (kk >> 1)], w);
        }
        if (!(kk & 3))  // A slab h half bf16 (u64 idx 0..63 of row bb)
          ast64(&A64[(size_t)t * 2048 + bb * 128 + b * 4 + (kk >> 2)],
                pack4(hn, h1, h2, h3));
      }
      VM0;
      if (tid == 0) ast32(&arrive2[b * 16], (U32)(t + 1));
      bar16(arrive2, (U32)(t + 1), lane, wv);
      if (tid < 4) ast32(&release[(b * 4 + tid) * 16], (U32)(t + 1));
      // ---- phase C: reload h, hWs(next), p_gen
      if (tid < 128) {
        U64 v = ald64(&Hex[b * 128 + tid]);
        h_cur[2 * tid] = __uint_as_float((U32)v);
        h_cur[2 * tid + 1] = __uint_as_float((U32)(v >> 32));
      }
      __syncthreads();
      {
        float acc = 0.f;
#pragma unroll 8
        for (int j = 0; j < CH; ++j) acc += h_cur[j] * W_sT[j * CH + tid];
        hws_s[tid] = acc;
      }
      {
        float z = h_cur[tid] * W_pg[tid] + ctx_s[tid] * W_pg[CH + tid];
        if (tid < CE) z += emb_v * W_pg[2 * CH + tid];
        z = wave_sum(z);
        if (lane == 0) red[wv] = z;
        __syncthreads();
        if (tid == 0)
          p_gen_g[t * CB + b] =
              sigm(red[0] + red[1] + red[2] + red[3] + b_pg[0]);
      }
      __syncthreads();
    }
    // final covloss term (t=49) + totals + c_fin
    for (int s = tid; s < CS; s += 256) covl += fminf(a_s[s], cov_s[s]);
    covl = wave_sum(covl);
    if (lane == 0) red[wv] = covl;
    __syncthreads();
    if (tid == 0) covloss_b[b] = red[0] + red[1] + red[2] + red[3];
    c_fin[(tid >> 4) * CH + b * 16 + (tid & 15)] = c_reg;
  } else {
    // ======================= VOCAB LANE =======================
    const int vb = bid - CB;
    const int nn = lane & 15, g = lane >> 4;
    U64* a64l = sh_big;  // [16][130] u64 (65 short8 stride)
    const short8* lds8 = (const short8*)sh_big;
    for (int t = 0; t < CTM1; ++t) {
      if (tid == 0) {  // poll own replica line, low frequency
        int gg = 0;
        while (ald32(&release[(vb & 63) * 16]) < (U32)(t + 1) &&
               ++gg < (1 << 18))
          __builtin_amdgcn_s_sleep(16);
      }
      __syncthreads();
      {  // stage A slab (uncached) -> LDS
        const U64* src = A64 + (size_t)t * 2048;
#pragma unroll
        for (int i = 0; i < 8; ++i) {
          int idx = tid + i * 256;
          int row = idx >> 7, col = idx & 127;
          a64l[row * 130 + col] = ald64(&src[idx]);
        }
      }
      if (tid < 16) rsum_loc[tid] = 0.f;
      __syncthreads();
      short8 af[16];
#pragma unroll
      for (int kt = 0; kt < 16; ++kt) af[kt] = lds8[nn * 65 + kt * 4 + g];
      for (int tile = vb; tile < NTILE; tile += NVB) {
        int v = tile * 64 + wv * 16 + nn;
        bool ok = v < CV;
        int vc = ok ? v : CV - 1;
        const short8* bp = (const short8*)Wb + (size_t)vc * 64;  // cached!
        f32x4 acc = {0.f, 0.f, 0.f, 0.f};
#pragma unroll
        for (int kt = 0; kt < 16; ++kt)
          acc = __builtin_amdgcn_mfma_f32_16x16x32_bf16(af[kt], bp[kt * 4 + g],
                                                        acc, 0, 0, 0);
        float bo = ok ? b_out[v] : 0.f;
        float ev[4];
#pragma unroll
        for (int r = 0; r < 4; ++r) {
          float e = ok ? __expf(acc[r] + bo) : 0.f;
          if (ok) dout[((size_t)((g * 4 + r) * CTM1 + t)) * CEXT + v] = e;
#pragma unroll
          for (int o = 1; o < 16; o <<= 1) e += __shfl_xor(e, o);
          ev[r] = e;
        }
        if (nn == 0) {
#pragma unroll
          for (int r = 0; r < 4; ++r) prs[wv][g * 4 + r] = ev[r];
        }
        __syncthreads();
        if (tid < 16)
          rsum_loc[tid] +=
              prs[0][tid] + prs[1][tid] + prs[2][tid] + prs[3][tid];
        __syncthreads();
      }
      if (tid < 16)
        atomicAdd(&part[((size_t)t * CB + tid) * 64 + (vb & 63)],
                  rsum_loc[tid]);
    }
  }
}

// ---------------------------------------------------------------------------
// POST 1: per (b,t) row: reduce 64 rowsum partials, normalize + zero pads.
// grid = 800.
// ---------------------------------------------------------------------------
__global__ __launch_bounds__(256) void post_norm(
    const float* __restrict__ part, const float* __restrict__ p_gen_g,
    float* __restrict__ dout) {
  const int R = blockIdx.x;
  const int b = R / CTM1, t = R % CTM1;
  const int tid = threadIdx.x;
  __shared__ float stat;
  float s = (tid < 64) ? part[((size_t)t * CB + b) * 64 + tid] : 0.f;
  s = wave_sum(s);
  if (tid == 0) stat = p_gen_g[t * CB + b] / s;
  __syncthreads();
  float inv = stat;
  float* drow = dout + (size_t)R * CEXT;
  for (int v = tid; v < CEXT; v += 256)
    drow[v] = (v < CV) ? drow[v] * inv : 0.f;
}

// ---------------------------------------------------------------------------
// POST 2: copy-dist scatter for all t + hT/cT + coverage_loss. grid = 16.
// ---------------------------------------------------------------------------
__global__ __launch_bounds__(256) void post_tail(
    const unsigned short* __restrict__ attn16,
    const float* __restrict__ p_gen_g, const int* __restrict__ copy_idx,
    const float* __restrict__ hexf, const float* __restrict__ c_fin,
    const float* __restrict__ covloss_b, float* __restrict__ dout) {
  const int b = blockIdx.x, tid = threadIdx.x;
  for (int t = 0; t < CTM1; ++t) {
    float pg1 = 1.f - p_gen_g[t * CB + b];
    const unsigned short* ar = attn16 + ((size_t)t * CB + b) * CS;
    float* drow = dout + ((size_t)(b * CTM1 + t)) * CEXT;
    for (int s = tid; s < CS; s += 256)
      atomicAdd(drow + copy_idx[b * CS + s], pg1 * bf2f(ar[s]));
  }
  const size_t D0 = (size_t)CB * CTM1 * CEXT;
  dout[D0 + b * CH + tid] = hexf[b * CH + tid];
  dout[D0 + CB * CH + b * CH + tid] = c_fin[b * CH + tid];
  if (b == 0 && tid == 0) {
    float s = 0.f;
    for (int i = 0; i < CB; ++i) s += covloss_b[i];
    dout[D0 + 2 * CB * CH] = s / (float)(CTM1 * CB);
  }
}

// ---------------------------------------------------------------------------
extern "C" void kernel_launch(void* const* d_in, const int* in_sizes, int n_in,
                              void* d_out, int out_size, void* d_ws,
                              size_t ws_size, hipStream_t stream) {
  const int* tgt = (const int*)d_in[0];
  const float* hidden = (const float*)d_in[1];
  const float* cell = (const float*)d_in[2];
  const float* enc = (const float*)d_in[3];
  const int* src_lens = (const int*)d_in[4];
  const int* src_ids = (const int*)d_in[5];
  const int* src_oov = (const int*)d_in[6];
  const float* embedding = (const float*)d_in[7];
  const float* W_h = (const float*)d_in[8];
  const float* W_s = (const float*)d_in[9];
  const float* w_c = (const float*)d_in[10];
  const float* v_vec = (const float*)d_in[11];
  const float* b_attn = (const float*)d_in[12];
  const float* W_ih = (const float*)d_in[13];
  const float* W_hh = (const float*)d_in[14];
  const float* b_ih = (const float*)d_in[15];
  const float* b_hh = (const float*)d_in[16];
  const float* W_pg = (const float*)d_in[17];
  const float* b_pg = (const float*)d_in[18];
  const float* W_out = (const float*)d_in[19];
  const float* b_out = (const float*)d_in[20];
  float* dout = (float*)d_out;

  // workspace layout
  float* ws = (float*)d_ws;
  float* Wh_h = ws;                                  // 1,638,400 f
  float* W_sT = Wh_h + (size_t)CB * CS * CH;         // 65,536 f
  float* p_gen_g = W_sT + CH * CH;                   // 800 f
  float* part = p_gen_g + CTM1 * CB;                 // 51,200 f
  float* covloss_b = part + CTM1 * CB * 64;          // 16 f
  float* c_fin = covloss_b + 16;                     // 4,096 f
  int* copy_idx = (int*)(c_fin + CB * CH);           // 6,400 i
  U32* ctrl = (U32*)(copy_idx + CB * CS);            // 1,536 u32
  U64* Hex = (U64*)(ctrl + 1536);                    // 2,048 u64
  U64* Xg = Hex + CB * 128;                          // 2,560 u64
  U64* A64 = Xg + CB * 160;                          // 102,400 u64
  unsigned short* attn16 =
      (unsigned short*)(A64 + (size_t)CTM1 * CB * 128);        // 320,000 sh
  unsigned short* Wcat = attn16 + (size_t)CTM1 * CB * CS;      // 655,360 sh
  unsigned short* Wb = Wcat + (size_t)(4 * CH) * CX;           // 25,600,000 sh
  float* W_hT = (float*)A64;  // alias: used only before mega overwrites A64

  z_init<<<64, 256, 0, stream>>>(ctrl, part);
  pw_convert<<<(CV * 2 * CH) / (256 * 8), 256, 0, stream>>>(W_out, Wb);
  pw_cat<<<((4 * CH) * CX / 8) / 256, 256, 0, stream>>>(W_ih, W_hh, Wcat);
  pw_t256<<<CH, CH, 0, stream>>>(W_s, W_sT);
  pw_t256<<<CH, CH, 0, stream>>>(W_h, W_hT);
  p0_precompute<<<CB * CS / 8, 256, 0, stream>>>(enc, W_hT, src_ids, src_oov,
                                                 Wh_h, copy_idx);

  void* kargs[] = {
      (void*)&tgt,      (void*)&hidden,  (void*)&cell,      (void*)&enc,
      (void*)&src_lens, (void*)&embedding, (void*)&w_c,     (void*)&v_vec,
      (void*)&b_attn,   (void*)&b_ih,    (void*)&b_hh,      (void*)&W_pg,
      (void*)&b_pg,     (void*)&b_out,   (void*)&Wh_h,      (void*)&W_sT,
      (void*)&Wcat,     (void*)&Wb,      (void*)&Xg,        (void*)&A64,
      (void*)&Hex,      (void*)&attn16,  (void*)&p_gen_g,   (void*)&part,
      (void*)&c_fin,    (void*)&covloss_b, (void*)&ctrl,    (void*)&dout};
  hipError_t e = hipLaunchCooperativeKernel((const void*)mega, dim3(NBLK),
                                            dim3(256), kargs, 0, stream);
  if (e != hipSuccess) {
    // all NBLK blocks co-resident at this occupancy; plain launch fallback
    hipLaunchKernelGGL(mega, dim3(NBLK), dim3(256), 0, stream, tgt, hidden,
                       cell, enc, src_lens, embedding, w_c, v_vec, b_attn,
                       b_ih, b_hh, W_pg, b_pg, b_out, Wh_h, W_sT, Wcat, Wb,
                       Xg, A64, Hex, attn16, p_gen_g, part, c_fin, covloss_b,
                       ctrl, dout);
  }
  post_norm<<<CB * CTM1, 256, 0, stream>>>(part, p_gen_g, dout);
  post_tail<<<CB, 256, 0, stream>>>(attn16, p_gen_g, copy_idx,
                                    (const float*)Hex, c_fin, covloss_b, dout);
}

// Round 7
// 7632.616 us; speedup vs baseline: 1.9624x; 1.2887x over previous
//
#include <hip/hip_runtime.h>
#include <math.h>

// Problem constants
#define CB 16
#define CS 400
#define CT 51
#define CTM1 50
#define CV 50000
#define CE 128
#define CH 256
#define CMAXOOV 50
#define CEXT (CV + CMAXOOV)
#define CX 640             // E + H + H  (x = [emb|ctx|h])
#define NST 16             // state blocks
#define NWK 767            // vocab worker blocks
#define NBLK 784           // 16 state + 1 aggregator + 767 workers
#define NTILE 782          // ceil(V/64)

typedef __attribute__((ext_vector_type(4))) float f32x4;
typedef __attribute__((ext_vector_type(8))) short short8;
typedef unsigned int U32;
typedef unsigned long long U64;

__device__ __forceinline__ float wave_sum(float x) {
#pragma unroll
  for (int o = 32; o > 0; o >>= 1) x += __shfl_xor(x, o);
  return x;
}
__device__ __forceinline__ float sigm(float x) {
  return 1.f / (1.f + __expf(-x));
}
__device__ __forceinline__ float ftanh(float x) {
  x = fminf(fmaxf(x, -15.f), 15.f);
  float e = __expf(2.f * x);
  return (e - 1.f) / (e + 1.f);
}
__device__ __forceinline__ unsigned short f2bf(float f) {
  union { float f; U32 u; } x;
  x.f = f;
  U32 r = x.u + 0x7FFFu + ((x.u >> 16) & 1u);  // RNE
  return (unsigned short)(r >> 16);
}
__device__ __forceinline__ float bf2f(unsigned short u) {
  return __uint_as_float(((U32)u) << 16);
}
__device__ __forceinline__ U64 pack4(float a, float b, float c, float d) {
  return (U64)f2bf(a) | ((U64)f2bf(b) << 16) | ((U64)f2bf(c) << 32) |
         ((U64)f2bf(d) << 48);
}
// uncached (device-coherent) ops — used ONLY for tiny sync/exchange data
__device__ __forceinline__ U32 ald32(const U32* p) {
  return __hip_atomic_load(p, __ATOMIC_RELAXED, __HIP_MEMORY_SCOPE_AGENT);
}
__device__ __forceinline__ U64 ald64(const U64* p) {
  return __hip_atomic_load(p, __ATOMIC_RELAXED, __HIP_MEMORY_SCOPE_AGENT);
}
__device__ __forceinline__ void ast32(U32* p, U32 v) {
  __hip_atomic_store(p, v, __ATOMIC_RELAXED, __HIP_MEMORY_SCOPE_AGENT);
}
__device__ __forceinline__ void ast64(U64* p, U64 v) {
  __hip_atomic_store(p, v, __ATOMIC_RELAXED, __HIP_MEMORY_SCOPE_AGENT);
}
#define VM0 asm volatile("s_waitcnt vmcnt(0)" ::: "memory")

// ---------------------------------------------------------------------------
// One-time weight prep
// ---------------------------------------------------------------------------
__global__ __launch_bounds__(256) void pw_convert(
    const float* __restrict__ W, unsigned short* __restrict__ Wb) {
  size_t i = ((size_t)blockIdx.x * 256 + threadIdx.x) * 8;
  float4 a = *(const float4*)(W + i);
  float4 b = *(const float4*)(W + i + 4);
  short8 o;
  o[0] = (short)f2bf(a.x); o[1] = (short)f2bf(a.y);
  o[2] = (short)f2bf(a.z); o[3] = (short)f2bf(a.w);
  o[4] = (short)f2bf(b.x); o[5] = (short)f2bf(b.y);
  o[6] = (short)f2bf(b.z); o[7] = (short)f2bf(b.w);
  *(short8*)(Wb + i) = o;
}

// WcatT[k][j] bf16 (transposed cat of W_ih|W_hh): k<384 -> W_ih[j][k],
// else W_hh[j][k-384].  [640][1024].
__global__ __launch_bounds__(256) void pw_catT(
    const float* __restrict__ W_ih, const float* __restrict__ W_hh,
    unsigned short* __restrict__ WcatT) {
  int gid = blockIdx.x * 256 + threadIdx.x;  // 655,360
  int k = gid >> 10, j = gid & 1023;
  float v = (k < CE + CH) ? W_ih[(size_t)j * (CE + CH) + k]
                          : W_hh[(size_t)j * CH + (k - (CE + CH))];
  WcatT[gid] = f2bf(v);
}

// 256x256 fp32 transpose: out[j][k] = in[k][j]
__global__ __launch_bounds__(256) void pw_t256(const float* __restrict__ in,
                                               float* __restrict__ out) {
  int j = blockIdx.x, k = threadIdx.x;
  out[j * CH + k] = in[k * CH + j];
}

// ---------------------------------------------------------------------------
// P0: Wh_h = enc @ W_h^T (coalesced via W_hT); copy_idx.
// ---------------------------------------------------------------------------
__global__ __launch_bounds__(256) void p0_precompute(
    const float* __restrict__ enc, const float* __restrict__ W_hT,
    const int* __restrict__ src_ids, const int* __restrict__ src_oov,
    float* __restrict__ Wh_h, int* __restrict__ copy_idx) {
  const int row0 = blockIdx.x * 8, tid = threadIdx.x;
  __shared__ float erT[CH * 8];
#pragma unroll
  for (int i = 0; i < 8; ++i) {
    int idx = tid + i * 256;
    int r = idx >> 8, j = idx & 255;
    erT[j * 8 + r] = enc[(size_t)row0 * CH + idx];
  }
  if (tid < 8) {
    int row = row0 + tid;
    int ov = src_oov[row];
    copy_idx[row] = (ov >= 0) ? (CV + ov) : src_ids[row];
  }
  __syncthreads();
  float acc[8] = {0, 0, 0, 0, 0, 0, 0, 0};
#pragma unroll 4
  for (int j = 0; j < CH; ++j) {
    float w = W_hT[j * CH + tid];
    float4 e0 = *(const float4*)&erT[j * 8];
    float4 e1 = *(const float4*)&erT[j * 8 + 4];
    acc[0] += e0.x * w; acc[1] += e0.y * w; acc[2] += e0.z * w; acc[3] += e0.w * w;
    acc[4] += e1.x * w; acc[5] += e1.y * w; acc[6] += e1.z * w; acc[7] += e1.w * w;
  }
#pragma unroll
  for (int r = 0; r < 8; ++r) Wh_h[(size_t)(row0 + r) * CH + tid] = acc[r];
}

// ---------------------------------------------------------------------------
// Z: zero control words + rowsum partials (every call: replay-safe).
// ctrl: arrive[16 slots, stride 16] @0 ; release[64 replicas, stride 16] @256
// ---------------------------------------------------------------------------
__global__ __launch_bounds__(256) void z_init(U32* __restrict__ ctrl,
                                              float* __restrict__ part) {
  int tid = blockIdx.x * 256 + threadIdx.x;
  if (tid < 2048) ctrl[tid] = 0u;
  for (int i = tid; i < CTM1 * CB * 64; i += 256 * 64) part[i] = 0.f;
}

// ---------------------------------------------------------------------------
// MEGA: 16 independent state blocks + 1 aggregator + 767 vocab workers.
// ZERO intra-step cross-block synchronization on the state critical path.
// ---------------------------------------------------------------------------
__global__ __launch_bounds__(256, 4) void mega(
    const int* __restrict__ tgt, const float* __restrict__ hidden,
    const float* __restrict__ cell, const float* __restrict__ enc,
    const int* __restrict__ src_lens, const float* __restrict__ embedding,
    const float* __restrict__ w_c, const float* __restrict__ v_vec,
    const float* __restrict__ b_attn, const float* __restrict__ b_ih,
    const float* __restrict__ b_hh, const float* __restrict__ W_pg,
    const float* __restrict__ b_pg, const float* __restrict__ b_out,
    const float* __restrict__ Wh_h, const float* __restrict__ W_sT,
    const unsigned short* __restrict__ WcatT,
    const unsigned short* __restrict__ Wb, U64* __restrict__ A64,
    unsigned short* __restrict__ attn16, float* __restrict__ p_gen_g,
    float* __restrict__ part, float* __restrict__ covloss_b,
    U32* __restrict__ ctrl, float* __restrict__ dout) {
  const int bid = blockIdx.x, tid = threadIdx.x;
  const int lane = tid & 63, wv = tid >> 6;
  U32* arrive = ctrl;          // 16 slots, stride 16
  U32* release = ctrl + 256;   // 64 replicas, stride 16

  __shared__ __align__(16) U64 sh_big[2080];  // vocab: A LDS [16][130]
  __shared__ float cov_s[CS];
  __shared__ float a_s[CS];
  __shared__ __align__(16) float h_cur[CH];
  __shared__ float hws_s[CH];
  __shared__ __align__(16) float ctx_s[CH];
  __shared__ float x_f[CX];
  __shared__ float g_sh[4 * CH];
  __shared__ float red[4];
  __shared__ float stat[4];
  __shared__ float prs[4][16];
  __shared__ float rsum_loc[16];

  if (bid < NST) {
    // ============== STATE LANE (batch b) — no cross-block waits ==========
    const int b = bid;
    const int len = src_lens[b];
    const float ba = b_attn[0];
    const int k4 = lane * 4;
    const float4 wc4 = *(const float4*)(w_c + k4);
    const float4 vv4 = *(const float4*)(v_vec + k4);
    // per-thread constants
    float bias0 = b_ih[tid * 4] + b_hh[tid * 4];
    float bias1 = b_ih[tid * 4 + 1] + b_hh[tid * 4 + 1];
    float bias2 = b_ih[tid * 4 + 2] + b_hh[tid * 4 + 2];
    float bias3 = b_ih[tid * 4 + 3] + b_hh[tid * 4 + 3];
    float covl = 0.f;
    float c_reg = cell[b * CH + tid];

    for (int i = tid; i < CS; i += 256) cov_s[i] = 0.f;
    h_cur[tid] = hidden[b * CH + tid];
    __syncthreads();
    {
      float acc = 0.f;
#pragma unroll 8
      for (int j = 0; j < CH; ++j) acc += h_cur[j] * W_sT[j * CH + tid];
      hws_s[tid] = acc;
    }
    __syncthreads();

    for (int t = 0; t < CTM1; ++t) {
      // -- coverage update + covloss(t-1)
      if (t > 0) {
        for (int s = tid; s < CS; s += 256) {
          float a = a_s[s], cv = cov_s[s];
          covl += fminf(a, cv);
          cov_s[s] = cv + a;
        }
        __syncthreads();
      }
      // -- scores (no-max exp): wave per s, lanes over k
      float ps = 0.f;
      for (int s = wv; s < CS; s += 4) {
        float cv = cov_s[s];
        float4 wh = *(const float4*)(Wh_h + ((size_t)(b * CS + s)) * CH + k4);
        float p = ftanh(wh.x + hws_s[k4] + cv * wc4.x + ba) * vv4.x +
                  ftanh(wh.y + hws_s[k4 + 1] + cv * wc4.y + ba) * vv4.y +
                  ftanh(wh.z + hws_s[k4 + 2] + cv * wc4.z + ba) * vv4.z +
                  ftanh(wh.w + hws_s[k4 + 3] + cv * wc4.w + ba) * vv4.w;
        p = wave_sum(p);
        if (lane == 0) {
          float e = (s < len) ? __expf(p) : 0.f;  // |score| <~ 10: safe
          a_s[s] = e;
          ps += e;
        }
      }
      if (lane == 0) red[wv] = ps;
      __syncthreads();
      if (tid == 0) stat[0] = 1.f / (red[0] + red[1] + red[2] + red[3]);
      __syncthreads();
      const float inv = stat[0];
      for (int s = tid; s < CS; s += 256) {
        float a = a_s[s] * inv;
        a_s[s] = a;
        attn16[((size_t)t * CB + b) * CS + s] = f2bf(a);
      }
      __syncthreads();
      // -- context (thread owns k=tid), x assembly
      {
        float pc = 0.f;
        const float* er = enc + ((size_t)b * CS) * CH + tid;
#pragma unroll 16
        for (int s = 0; s < CS; ++s) pc += a_s[s] * er[(size_t)s * CH];
        ctx_s[tid] = pc;
        x_f[CE + tid] = pc;
        x_f[CE + CH + tid] = h_cur[tid];
      }
      const int tok = tgt[b * CT + t];
      float emb_v = 0.f;
      if (tid < CE) {
        emb_v = embedding[(size_t)tok * CE + tid];
        x_f[tid] = emb_v;
      }
      __syncthreads();
      // -- gates (batch-local, VALU, bf16 WcatT stream): cols tid*4..+3
      {
        float a0 = 0.f, a1 = 0.f, a2 = 0.f, a3 = 0.f;
        const U64* wt = (const U64*)WcatT;
#pragma unroll 4
        for (int k = 0; k < CX; ++k) {
          U64 w = wt[(size_t)k * 256 + tid];
          float xk = x_f[k];
          a0 += xk * bf2f((unsigned short)w);
          a1 += xk * bf2f((unsigned short)(w >> 16));
          a2 += xk * bf2f((unsigned short)(w >> 32));
          a3 += xk * bf2f((unsigned short)(w >> 48));
        }
        g_sh[tid * 4] = a0 + bias0;
        g_sh[tid * 4 + 1] = a1 + bias1;
        g_sh[tid * 4 + 2] = a2 + bias2;
        g_sh[tid * 4 + 3] = a3 + bias3;
      }
      __syncthreads();
      // -- cell update (thread owns unit u=tid)
      float hn;
      {
        float gi = g_sh[tid], gf = g_sh[CH + tid];
        float gg2 = g_sh[2 * CH + tid], go = g_sh[3 * CH + tid];
        float cn = sigm(gf) * c_reg + sigm(gi) * ftanh(gg2);
        c_reg = cn;
        hn = sigm(go) * ftanh(cn);
        h_cur[tid] = hn;
      }
      __syncthreads();
      // -- publish A row b = [h(bf16 x256) | ctx(bf16 x256)] via UC stores
      if (tid < 64) {
        ast64(&A64[(size_t)t * 2048 + b * 128 + tid],
              pack4(h_cur[4 * tid], h_cur[4 * tid + 1], h_cur[4 * tid + 2],
                    h_cur[4 * tid + 3]));
      } else if (tid < 128) {
        int i = tid - 64;
        ast64(&A64[(size_t)t * 2048 + b * 128 + 64 + i],
              pack4(ctx_s[4 * i], ctx_s[4 * i + 1], ctx_s[4 * i + 2],
                    ctx_s[4 * i + 3]));
      }
      VM0;
      if (tid == 0) ast32(&arrive[b * 16], (U32)(t + 1));
      // -- off-critical-path: hWs(next) + p_gen
      {
        float acc = 0.f;
#pragma unroll 8
        for (int j = 0; j < CH; ++j) acc += h_cur[j] * W_sT[j * CH + tid];
        hws_s[tid] = acc;
      }
      {
        float z = hn * W_pg[tid] + ctx_s[tid] * W_pg[CH + tid];
        if (tid < CE) z += emb_v * W_pg[2 * CH + tid];
        z = wave_sum(z);
        if (lane == 0) red[wv] = z;
        __syncthreads();
        if (tid == 0)
          p_gen_g[t * CB + b] =
              sigm(red[0] + red[1] + red[2] + red[3] + b_pg[0]);
      }
      __syncthreads();
    }
    // tail: covloss t=49 term, totals, hT/cT straight into dout
    for (int s = tid; s < CS; s += 256) covl += fminf(a_s[s], cov_s[s]);
    covl = wave_sum(covl);
    if (lane == 0) red[wv] = covl;
    __syncthreads();
    if (tid == 0) covloss_b[b] = red[0] + red[1] + red[2] + red[3];
    const size_t D0 = (size_t)CB * CTM1 * CEXT;
    dout[D0 + b * CH + tid] = h_cur[tid];
    dout[D0 + CB * CH + b * CH + tid] = c_reg;
  } else if (bid == NST) {
    // ===================== AGGREGATOR (1 block) ==========================
    for (int t = 0; t < CTM1; ++t) {
      if (wv == 0) {
        int gg = 0;
        while (gg < (1 << 17)) {
          U32 v = (lane < NST) ? ald32(&arrive[lane * 16]) : (U32)(t + 1);
          if (__all(v >= (U32)(t + 1))) break;
          __builtin_amdgcn_s_sleep(8);
          ++gg;
        }
      }
      __syncthreads();
      if (tid < 64) ast32(&release[tid * 16], (U32)(t + 1));
      __syncthreads();
    }
  } else {
    // ===================== VOCAB WORKERS (767 blocks) ====================
    const int vb = bid - NST - 1;
    const int nn = lane & 15, g = lane >> 4;
    U64* a64l = sh_big;  // [16][130] u64 (65-short8 row stride)
    const short8* lds8 = (const short8*)sh_big;
    for (int t = 0; t < CTM1; ++t) {
      if (tid == 0) {  // poll own replica; self-throttles while working
        int gg = 0;
        while (ald32(&release[(vb & 63) * 16]) < (U32)(t + 1) &&
               ++gg < (1 << 17))
          __builtin_amdgcn_s_sleep(64);
      }
      __syncthreads();
      {  // stage A slab (UC) -> LDS
        const U64* src = A64 + (size_t)t * 2048;
#pragma unroll
        for (int i = 0; i < 8; ++i) {
          int idx = tid + i * 256;
          int row = idx >> 7, col = idx & 127;
          a64l[row * 130 + col] = ald64(&src[idx]);
        }
      }
      if (tid < 16) rsum_loc[tid] = 0.f;
      __syncthreads();
      short8 af[16];
#pragma unroll
      for (int kt = 0; kt < 16; ++kt) af[kt] = lds8[nn * 65 + kt * 4 + g];
      for (int tile = vb; tile < NTILE; tile += NWK) {
        int v = tile * 64 + wv * 16 + nn;
        bool ok = v < CV;
        int vc = ok ? v : CV - 1;
        const short8* bp = (const short8*)Wb + (size_t)vc * 64;  // cached
        f32x4 acc = {0.f, 0.f, 0.f, 0.f};
#pragma unroll
        for (int kt = 0; kt < 16; ++kt)
          acc = __builtin_amdgcn_mfma_f32_16x16x32_bf16(af[kt], bp[kt * 4 + g],
                                                        acc, 0, 0, 0);
        float bo = ok ? b_out[v] : 0.f;
        float ev[4];
#pragma unroll
        for (int r = 0; r < 4; ++r) {
          float e = ok ? __expf(acc[r] + bo) : 0.f;
          if (ok) dout[((size_t)((g * 4 + r) * CTM1 + t)) * CEXT + v] = e;
#pragma unroll
          for (int o = 1; o < 16; o <<= 1) e += __shfl_xor(e, o);
          ev[r] = e;
        }
        if (nn == 0) {
#pragma unroll
          for (int r = 0; r < 4; ++r) prs[wv][g * 4 + r] = ev[r];
        }
        __syncthreads();
        if (tid < 16)
          rsum_loc[tid] +=
              prs[0][tid] + prs[1][tid] + prs[2][tid] + prs[3][tid];
        __syncthreads();
      }
      if (tid < 16)
        atomicAdd(&part[((size_t)t * CB + tid) * 64 + (vb & 63)],
                  rsum_loc[tid]);
    }
  }
}

// ---------------------------------------------------------------------------
// POST 1: per (b,t) row: reduce 64 rowsum partials, normalize + zero pads.
// ---------------------------------------------------------------------------
__global__ __launch_bounds__(256) void post_norm(
    const float* __restrict__ part, const float* __restrict__ p_gen_g,
    float* __restrict__ dout) {
  const int R = blockIdx.x;
  const int b = R / CTM1, t = R % CTM1;
  const int tid = threadIdx.x;
  __shared__ float stat;
  float s = (tid < 64) ? part[((size_t)t * CB + b) * 64 + tid] : 0.f;
  s = wave_sum(s);
  if (tid == 0) stat = p_gen_g[t * CB + b] / s;
  __syncthreads();
  float inv = stat;
  float* drow = dout + (size_t)R * CEXT;
  for (int v = tid; v < CEXT; v += 256)
    drow[v] = (v < CV) ? drow[v] * inv : 0.f;
}

// ---------------------------------------------------------------------------
// POST 2: copy-dist scatter for all t + coverage_loss. grid = 16.
// ---------------------------------------------------------------------------
__global__ __launch_bounds__(256) void post_tail(
    const unsigned short* __restrict__ attn16,
    const float* __restrict__ p_gen_g, const int* __restrict__ copy_idx,
    const float* __restrict__ covloss_b, float* __restrict__ dout) {
  const int b = blockIdx.x, tid = threadIdx.x;
  for (int t = 0; t < CTM1; ++t) {
    float pg1 = 1.f - p_gen_g[t * CB + b];
    const unsigned short* ar = attn16 + ((size_t)t * CB + b) * CS;
    float* drow = dout + ((size_t)(b * CTM1 + t)) * CEXT;
    for (int s = tid; s < CS; s += 256)
      atomicAdd(drow + copy_idx[b * CS + s], pg1 * bf2f(ar[s]));
  }
  if (b == 0 && tid == 0) {
    const size_t D0 = (size_t)CB * CTM1 * CEXT;
    float s = 0.f;
    for (int i = 0; i < CB; ++i) s += covloss_b[i];
    dout[D0 + 2 * CB * CH] = s / (float)(CTM1 * CB);
  }
}

// ---------------------------------------------------------------------------
extern "C" void kernel_launch(void* const* d_in, const int* in_sizes, int n_in,
                              void* d_out, int out_size, void* d_ws,
                              size_t ws_size, hipStream_t stream) {
  const int* tgt = (const int*)d_in[0];
  const float* hidden = (const float*)d_in[1];
  const float* cell = (const float*)d_in[2];
  const float* enc = (const float*)d_in[3];
  const int* src_lens = (const int*)d_in[4];
  const int* src_ids = (const int*)d_in[5];
  const int* src_oov = (const int*)d_in[6];
  const float* embedding = (const float*)d_in[7];
  const float* W_h = (const float*)d_in[8];
  const float* W_s = (const float*)d_in[9];
  const float* w_c = (const float*)d_in[10];
  const float* v_vec = (const float*)d_in[11];
  const float* b_attn = (const float*)d_in[12];
  const float* W_ih = (const float*)d_in[13];
  const float* W_hh = (const float*)d_in[14];
  const float* b_ih = (const float*)d_in[15];
  const float* b_hh = (const float*)d_in[16];
  const float* W_pg = (const float*)d_in[17];
  const float* b_pg = (const float*)d_in[18];
  const float* W_out = (const float*)d_in[19];
  const float* b_out = (const float*)d_in[20];
  float* dout = (float*)d_out;

  // workspace layout (16B alignment maintained)
  float* ws = (float*)d_ws;
  float* Wh_h = ws;                                  // 1,638,400 f
  float* W_sT = Wh_h + (size_t)CB * CS * CH;         // 65,536 f
  float* W_hT = W_sT + CH * CH;                      // 65,536 f
  float* p_gen_g = W_hT + CH * CH;                   // 800 f
  float* part = p_gen_g + CTM1 * CB;                 // 51,200 f
  float* covloss_b = part + CTM1 * CB * 64;          // 16 f
  int* copy_idx = (int*)(covloss_b + 16);            // 6,400 i
  U32* ctrl = (U32*)(copy_idx + CB * CS);            // 2,048 u32
  U64* A64 = (U64*)(ctrl + 2048);                    // 102,400 u64
  unsigned short* attn16 =
      (unsigned short*)(A64 + (size_t)CTM1 * 2048);  // 320,000 sh
  unsigned short* WcatT = attn16 + (size_t)CTM1 * CB * CS;  // 655,360 sh
  unsigned short* Wb = WcatT + (size_t)CX * 1024;    // 25,600,000 sh

  z_init<<<64, 256, 0, stream>>>(ctrl, part);
  pw_convert<<<(CV * 2 * CH) / (256 * 8), 256, 0, stream>>>(W_out, Wb);
  pw_catT<<<(CX * 1024) / 256, 256, 0, stream>>>(W_ih, W_hh, WcatT);
  pw_t256<<<CH, CH, 0, stream>>>(W_s, W_sT);
  pw_t256<<<CH, CH, 0, stream>>>(W_h, W_hT);
  p0_precompute<<<CB * CS / 8, 256, 0, stream>>>(enc, W_hT, src_ids, src_oov,
                                                 Wh_h, copy_idx);

  void* kargs[] = {
      (void*)&tgt,      (void*)&hidden,    (void*)&cell,     (void*)&enc,
      (void*)&src_lens, (void*)&embedding, (void*)&w_c,      (void*)&v_vec,
      (void*)&b_attn,   (void*)&b_ih,      (void*)&b_hh,     (void*)&W_pg,
      (void*)&b_pg,     (void*)&b_out,     (void*)&Wh_h,     (void*)&W_sT,
      (void*)&WcatT,    (void*)&Wb,        (void*)&A64,      (void*)&attn16,
      (void*)&p_gen_g,  (void*)&part,      (void*)&covloss_b,(void*)&ctrl,
      (void*)&dout};
  hipError_t e = hipLaunchCooperativeKernel((const void*)mega, dim3(NBLK),
                                            dim3(256), kargs, 0, stream);
  if (e != hipSuccess) {
    hipLaunchKernelGGL(mega, dim3(NBLK), dim3(256), 0, stream, tgt, hidden,
                       cell, enc, src_lens, embedding, w_c, v_vec, b_attn,
                       b_ih, b_hh, W_pg, b_pg, b_out, Wh_h, W_sT, WcatT, Wb,
                       A64, attn16, p_gen_g, part, covloss_b, ctrl, dout);
  }
  post_norm<<<CB * CTM1, 256, 0, stream>>>(part, p_gen_g, dout);
  post_tail<<<CB, 256, 0, stream>>>(attn16, p_gen_g, copy_idx, covloss_b,
                                    dout);
}